// Round 15
// baseline (931.619 us; speedup 1.0000x reference)
//
#include <hip/hip_runtime.h>

#define BB 8
#define CC 64
#define OO 128
#define NN 4096
#define KNN 20
#define NT 256          // 16-j tiles per batch scan (full 4096 j)
#define NCH 4           // merge chunks = per-row col-classes (g)
#define RING 17         // per-lane LDS ring slots
#define TRIG 13         // drain when any lane cnt>=13 (growth <=4/tile -> <=16)
#define SPLITW 192      // xsp row: 64 bf16 h | 64 bf16 m | 64 bf16 l (384 B)

typedef short bf16x8 __attribute__((ext_vector_type(8)));
typedef float f32x4 __attribute__((ext_vector_type(4)));

// ===========================================================================
// Top-20: UNSORTED slots + cached (kmax,kpos); kpos eviction + argmax tree.
// Proven R5-R14. NAMED SCALARS only (R2: no SROA).
// R15 theory: knn's ~410us plateau = 4 waves/block redundantly loading the
// SAME 6KB of B rows per tile with no barrier -> waves drift -> L1 can't
// serve repeats -> ~3GB L2 traffic + per-tile L2 latency exposure (87%
// stall by back-solve). Fix: __syncthreads() per tile keeps waves lockstep
// so waves 2-4 hit L1. Explains R11 (2x occupancy, same traffic, flat) and
// R12 (reg prefetch attacked latency, died by spill).
// ===========================================================================
#define REP20(F, P) F(P,0) F(P,1) F(P,2) F(P,3) F(P,4) F(P,5) F(P,6) F(P,7) \
    F(P,8) F(P,9) F(P,10) F(P,11) F(P,12) F(P,13) F(P,14) F(P,15) F(P,16)   \
    F(P,17) F(P,18) F(P,19)

#define TS_DECL(P,k) float P##m##k = 1e30f; int P##p##k = -1;
#define TS_REPL(P,k)                                                        \
  { const bool _h = (P##kpos == (k));                                       \
    P##m##k = _h ? _d : P##m##k;                                            \
    P##p##k = _h ? _j : P##p##k; }

#define TS_N(vd, xd, va, xa, vb, xb)                                        \
  { const bool _g = (vb) > (va); vd = _g ? (vb) : (va); xd = _g ? (xb) : (xa); }

#define TS_TREE(P)                                                          \
  { float t0,t1,t2,t3,t4,t5,t6,t7,t8,t9; int y0,y1,y2,y3,y4,y5,y6,y7,y8,y9; \
    TS_N(t0,y0, P##m0,0,  P##m1,1)   TS_N(t1,y1, P##m2,2,  P##m3,3)         \
    TS_N(t2,y2, P##m4,4,  P##m5,5)   TS_N(t3,y3, P##m6,6,  P##m7,7)         \
    TS_N(t4,y4, P##m8,8,  P##m9,9)   TS_N(t5,y5, P##m10,10, P##m11,11)      \
    TS_N(t6,y6, P##m12,12, P##m13,13) TS_N(t7,y7, P##m14,14, P##m15,15)     \
    TS_N(t8,y8, P##m16,16, P##m17,17) TS_N(t9,y9, P##m18,18, P##m19,19)     \
    float u0,u1,u2,u3,u4; int z0,z1,z2,z3,z4;                               \
    TS_N(u0,z0, t0,y0, t1,y1) TS_N(u1,z1, t2,y2, t3,y3)                     \
    TS_N(u2,z2, t4,y4, t5,y5) TS_N(u3,z3, t6,y6, t7,y7)                     \
    TS_N(u4,z4, t8,y8, t9,y9)                                               \
    float w0,w1; int q0,q1;                                                 \
    TS_N(w0,q0, u0,z0, u1,z1) TS_N(w1,q1, u2,z2, u3,z3)                     \
    float e0; int r0;                                                       \
    TS_N(e0,r0, w0,q0, w1,q1)                                               \
    TS_N(P##kmax, P##kpos, e0,r0, u4,z4) }

#define TS_INS(P, dval, jval)                                               \
  { const float _d = (dval); const int _j = (jval);                         \
    REP20(TS_REPL, P)                                                       \
    TS_TREE(P) }

// row-threshold refresh: rt = min(kmax over lanes {l, l^4, l^8, l^12})
// (the 4 lanes sharing myrow differ in lane-id bits 2,3 = col-class g).
// rt >= true row-d20 always; stale rt is larger => gate is safe (R13).
#define RT_UPDATE                                                           \
  { const int _s1 = __builtin_amdgcn_ds_swizzle(__float_as_int(A_kmax), 0x101F); \
    const float _m1 = fminf(A_kmax, __int_as_float(_s1));                   \
    const int _s2 = __builtin_amdgcn_ds_swizzle(__float_as_int(_m1), 0x201F); \
    rt = fminf(_m1, __int_as_float(_s2)); }

// ---------------------------------------------------------------------------
// round-to-nearest-even fp32 -> bf16 bits (no NaN/inf in this data)
// ---------------------------------------------------------------------------
__device__ __forceinline__ unsigned rne_bf16(float f) {
  const unsigned u = __float_as_uint(f);
  return (u + 0x7fffu + ((u >> 16) & 1u)) >> 16;
}

// ---------------------------------------------------------------------------
// Kernel 1: per-point precompute (unchanged from R14).
//   Ab16[b][n][o] = bf16(W1.x)
//   Q[b][n][o]    = W2.x - W1.x + bias (fp32)
//   xsq[b][n]     = ||x||^2   xsp[b][n] = bf16 3-split row {h,m,l}
// ---------------------------------------------------------------------------
__global__ __launch_bounds__(128, 3) void precompute_kernel(
    const float* __restrict__ x, const float* __restrict__ W,
    const float* __restrict__ bias, unsigned short* __restrict__ Ab16,
    float* __restrict__ Q, float* __restrict__ xsq,
    unsigned short* __restrict__ xsp) {
  const int b = blockIdx.y;
  const int n = blockIdx.x * 128 + threadIdx.x;
  const float* xb = x + (size_t)b * CC * NN;

  float xr[CC];
  float sq = 0.f;
#pragma unroll
  for (int c = 0; c < CC; ++c) {
    xr[c] = xb[(size_t)c * NN + n];  // coalesced across threads
    sq = fmaf(xr[c], xr[c], sq);
  }
  xsq[(size_t)b * NN + n] = sq;

  // bf16 3-split row
  unsigned* srow = (unsigned*)(xsp + ((size_t)b * NN + n) * SPLITW);
#pragma unroll
  for (int c = 0; c < CC; c += 2) {
    const unsigned h0 = rne_bf16(xr[c]), h1 = rne_bf16(xr[c + 1]);
    const float r0 = xr[c] - __uint_as_float(h0 << 16);
    const float r1 = xr[c + 1] - __uint_as_float(h1 << 16);
    const unsigned m0 = rne_bf16(r0), m1 = rne_bf16(r1);
    const float s0 = r0 - __uint_as_float(m0 << 16);
    const float s1 = r1 - __uint_as_float(m1 << 16);
    const unsigned l0 = rne_bf16(s0), l1 = rne_bf16(s1);
    srow[c / 2] = h0 | (h1 << 16);
    srow[32 + c / 2] = m0 | (m1 << 16);
    srow[64 + c / 2] = l0 | (l1 << 16);
  }

  unsigned short* Arow = Ab16 + ((size_t)b * NN + n) * OO;
  float* Qrow = Q + ((size_t)b * NN + n) * OO;

  for (int og = 0; og < OO; og += 4) {
    float p[4] = {0.f, 0.f, 0.f, 0.f};
    float g[4] = {0.f, 0.f, 0.f, 0.f};
#pragma unroll
    for (int oo = 0; oo < 4; ++oo) {
      const float* wr = W + (size_t)(og + oo) * (2 * CC);
#pragma unroll
      for (int c = 0; c < CC; c += 4) {
        float4 w1 = *(const float4*)(wr + c);
        float4 w2 = *(const float4*)(wr + CC + c);
        p[oo] = fmaf(w1.x, xr[c], p[oo]);
        p[oo] = fmaf(w1.y, xr[c + 1], p[oo]);
        p[oo] = fmaf(w1.z, xr[c + 2], p[oo]);
        p[oo] = fmaf(w1.w, xr[c + 3], p[oo]);
        g[oo] = fmaf(w2.x, xr[c], g[oo]);
        g[oo] = fmaf(w2.y, xr[c + 1], g[oo]);
        g[oo] = fmaf(w2.z, xr[c + 2], g[oo]);
        g[oo] = fmaf(w2.w, xr[c + 3], g[oo]);
      }
    }
    const unsigned pa0 = rne_bf16(p[0]) | (rne_bf16(p[1]) << 16);
    const unsigned pa1 = rne_bf16(p[2]) | (rne_bf16(p[3]) << 16);
    *(uint2*)(Arow + og) = make_uint2(pa0, pa1);
    float4 qv = make_float4(g[0] - p[0] + bias[og + 0], g[1] - p[1] + bias[og + 1],
                            g[2] - p[2] + bias[og + 2], g[3] - p[3] + bias[og + 3]);
    *(float4*)(Qrow + og) = qv;
  }
}

// ---------------------------------------------------------------------------
// Kernel 2: MFMA Gram-matrix kNN (R14 structure + per-tile __syncthreads).
// ---------------------------------------------------------------------------
#define TILE_MFMA(T, BUF)                                                   \
  { const unsigned short* brow = xspB + (size_t)((T) * 16 + c) * SPLITW + q * 8; \
    const bf16x8 Bh0 = *(const bf16x8*)(brow);                              \
    const bf16x8 Bh1 = *(const bf16x8*)(brow + 32);                         \
    const bf16x8 Bm0 = *(const bf16x8*)(brow + 64);                         \
    const bf16x8 Bm1 = *(const bf16x8*)(brow + 96);                         \
    const bf16x8 Bl0 = *(const bf16x8*)(brow + 128);                        \
    const bf16x8 Bl1 = *(const bf16x8*)(brow + 160);                        \
    f32x4 ac0 = {0.f, 0.f, 0.f, 0.f};                                       \
    f32x4 ac1 = {0.f, 0.f, 0.f, 0.f};                                       \
    f32x4 ac2 = {0.f, 0.f, 0.f, 0.f};                                       \
    f32x4 ac3 = {0.f, 0.f, 0.f, 0.f};                                       \
    ac0 = __builtin_amdgcn_mfma_f32_16x16x32_bf16(Ah0, Bh0, ac0, 0, 0, 0);  \
    ac1 = __builtin_amdgcn_mfma_f32_16x16x32_bf16(Ah1, Bh1, ac1, 0, 0, 0);  \
    ac2 = __builtin_amdgcn_mfma_f32_16x16x32_bf16(Ah0, Bm0, ac2, 0, 0, 0);  \
    ac3 = __builtin_amdgcn_mfma_f32_16x16x32_bf16(Ah1, Bm1, ac3, 0, 0, 0);  \
    ac0 = __builtin_amdgcn_mfma_f32_16x16x32_bf16(Am0, Bh0, ac0, 0, 0, 0);  \
    ac1 = __builtin_amdgcn_mfma_f32_16x16x32_bf16(Am1, Bh1, ac1, 0, 0, 0);  \
    ac2 = __builtin_amdgcn_mfma_f32_16x16x32_bf16(Ah0, Bl0, ac2, 0, 0, 0);  \
    ac3 = __builtin_amdgcn_mfma_f32_16x16x32_bf16(Ah1, Bl1, ac3, 0, 0, 0);  \
    ac0 = __builtin_amdgcn_mfma_f32_16x16x32_bf16(Al0, Bh0, ac0, 0, 0, 0);  \
    ac1 = __builtin_amdgcn_mfma_f32_16x16x32_bf16(Al1, Bh1, ac1, 0, 0, 0);  \
    ac2 = __builtin_amdgcn_mfma_f32_16x16x32_bf16(Am0, Bm0, ac2, 0, 0, 0);  \
    ac3 = __builtin_amdgcn_mfma_f32_16x16x32_bf16(Am1, Bm1, ac3, 0, 0, 0);  \
    const f32x4 acc = (ac0 + ac1) + (ac2 + ac3);                            \
    float* bw = &bounce[BUF][wv][0];                                        \
    bw[(q * 4 + 0) * 20 + c] = acc[0];                                      \
    bw[(q * 4 + 1) * 20 + c] = acc[1];                                      \
    bw[(q * 4 + 2) * 20 + c] = acc[2];                                      \
    bw[(q * 4 + 3) * 20 + c] = acc[3]; }

#define TILE_VALS(T, BUF)                                                   \
  const float* br = &bounce[BUF][wv][myrow * 20 + 4 * g];                   \
  const f32x4 dots = *(const f32x4*)br;                                     \
  const float4 xx = *(const float4*)(xsqb + (T) * 16 + 4 * g);              \
  const float d0 = fmaf(-2.f, dots[0], xx.x);                               \
  const float d1 = fmaf(-2.f, dots[1], xx.y);                               \
  const float d2 = fmaf(-2.f, dots[2], xx.z);                               \
  const float d3 = fmaf(-2.f, dots[3], xx.w);                               \
  const int jb = (T) * 16 + 4 * g;

// direct fill: first 20 stream values -> slots (no eviction needed)
#define TILE_SELF(T, BUF, K0, K1, K2, K3)                                   \
  { TILE_VALS(T, BUF)                                                       \
    A_m##K0 = d0; A_p##K0 = jb;                                             \
    A_m##K1 = d1; A_p##K1 = jb + 1;                                         \
    A_m##K2 = d2; A_p##K2 = jb + 2;                                         \
    A_m##K3 = d3; A_p##K3 = jb + 3; }

// rt-gated select: push iff d <= rt (rt >= d20row always => safe);
// drain keeps strict < kmax (first-seen/lower-j wins, as R5-R14).
#define TILE_SEL(T, BUF)                                                    \
  { TILE_VALS(T, BUF)                                                       \
    if (d0 <= rt) { myring[cnt] = make_float2(d0, __int_as_float(jb)); ++cnt; } \
    if (d1 <= rt) { myring[cnt] = make_float2(d1, __int_as_float(jb + 1)); ++cnt; } \
    if (d2 <= rt) { myring[cnt] = make_float2(d2, __int_as_float(jb + 2)); ++cnt; } \
    if (d3 <= rt) { myring[cnt] = make_float2(d3, __int_as_float(jb + 3)); ++cnt; } \
    if (__ballot(cnt >= TRIG)) {                                            \
      for (int _k = 0; _k < cnt; ++_k) {                                    \
        const float2 e = myring[_k];                                        \
        if (e.x < A_kmax) { TS_INS(A_, e.x, __float_as_int(e.y)) }          \
      }                                                                     \
      cnt = 0;                                                              \
    }                                                                       \
    RT_UPDATE }

__global__ __launch_bounds__(256, 3) void knn_kernel(
    const unsigned short* __restrict__ xsp, const float* __restrict__ xsq,
    float* __restrict__ cd, int* __restrict__ ci) {
  __shared__ float bounce[2][4][16 * 20];  // [buf][wave][row*20+col] 10 KB
  __shared__ float2 ring[256][RING];       // 34 KB

  const int b = blockIdx.y;
  const int wv = threadIdx.x >> 6;
  const int lane = threadIdx.x & 63;
  const int q = lane >> 4;
  const int c = lane & 15;
  const int ibase = blockIdx.x * 64 + wv * 16;
  const int myrow = q * 4 + (c & 3);  // owned output row (within wave tile)
  const int g = c >> 2;               // owned col-class = merge chunk
  const int isel = ibase + myrow;

  const unsigned short* xspB = xsp + (size_t)b * NN * SPLITW;
  const float* xsqb = xsq + (size_t)b * NN;

  // A fragments: rows ibase+c, k-slice quad*8 (+32 for k-chunk 1)
  const unsigned short* arow = xspB + (size_t)(ibase + c) * SPLITW + q * 8;
  const bf16x8 Ah0 = *(const bf16x8*)(arow);
  const bf16x8 Ah1 = *(const bf16x8*)(arow + 32);
  const bf16x8 Am0 = *(const bf16x8*)(arow + 64);
  const bf16x8 Am1 = *(const bf16x8*)(arow + 96);
  const bf16x8 Al0 = *(const bf16x8*)(arow + 128);
  const bf16x8 Al1 = *(const bf16x8*)(arow + 160);

  REP20(TS_DECL, A_)
  float A_kmax = 1e30f; int A_kpos = 0;
  float rt = 1e30f;
  float2* myring = ring[threadIdx.x];
  int cnt = 0;

  // pipelined: MFMA(t) overlaps select(t-1); first 5 selects direct-fill
  TILE_MFMA(0, 0)
  __syncthreads();
  TILE_MFMA(1, 1) TILE_SELF(0, 0, 0, 1, 2, 3)
  __syncthreads();
  TILE_MFMA(2, 0) TILE_SELF(1, 1, 4, 5, 6, 7)
  __syncthreads();
  TILE_MFMA(3, 1) TILE_SELF(2, 0, 8, 9, 10, 11)
  __syncthreads();
  TILE_MFMA(4, 0) TILE_SELF(3, 1, 12, 13, 14, 15)
  __syncthreads();
  TILE_MFMA(5, 1) TILE_SELF(4, 0, 16, 17, 18, 19)
  TS_TREE(A_)  // establish kmax/kpos from the 20 filled slots
  RT_UPDATE    // establish row threshold

#pragma unroll 2
  for (int t = 6; t < NT; ++t) {
    __syncthreads();  // R15: lockstep waves -> B rows L1-hit for waves 2-4
    const int pb = t & 1;
    TILE_MFMA(t, pb)
    TILE_SEL(t - 1, pb ^ 1)
  }
  TILE_SEL(NT - 1, 1)

  // final drain
  for (int _k = 0; _k < cnt; ++_k) {
    const float2 e = myring[_k];
    if (e.x < A_kmax) { TS_INS(A_, e.x, __float_as_int(e.y)) }
  }

  // candidate layout [b][ch=g][slot][n]; per-stream top-20, unsorted
  const size_t base = ((size_t)(b * NCH + g) * KNN) * NN + isel;
#define TS_ST(P,k) cd[base + (size_t)(k) * NN] = P##m##k; \
                   ci[base + (size_t)(k) * NN] = P##p##k;
  REP20(TS_ST, A_)
#undef TS_ST
}

// ---------------------------------------------------------------------------
// Kernel 3: merge NCH=4 unsorted 20-lists -> final top-20 index set.
// LEXICOGRAPHIC (d asc, j asc) compare = exact jax lower-index-wins.
// ---------------------------------------------------------------------------
#define TK_LIST(OP) OP(0) OP(1) OP(2) OP(3) OP(4) OP(5) OP(6) OP(7) OP(8) \
    OP(9) OP(10) OP(11) OP(12) OP(13) OP(14) OP(15) OP(16) OP(17) OP(18) OP(19)
#define TK_DECL(k) float td##k = 1e30f; int ti##k = -1;
#define TK_SW(a, b)                                                        \
  {                                                                        \
    const bool _s = (td##b < td##a) ||                                     \
                    ((td##b == td##a) && (ti##b < ti##a));                 \
    const float _fa = _s ? td##b : td##a;                                  \
    const float _fb = _s ? td##a : td##b;                                  \
    const int _ia = _s ? ti##b : ti##a;                                    \
    const int _ib = _s ? ti##a : ti##b;                                    \
    td##a = _fa; td##b = _fb; ti##a = _ia; ti##b = _ib;                    \
  }
#define TK_BUBBLE                                                          \
  TK_SW(18, 19) TK_SW(17, 18) TK_SW(16, 17) TK_SW(15, 16) TK_SW(14, 15)    \
  TK_SW(13, 14) TK_SW(12, 13) TK_SW(11, 12) TK_SW(10, 11) TK_SW(9, 10)     \
  TK_SW(8, 9) TK_SW(7, 8) TK_SW(6, 7) TK_SW(5, 6) TK_SW(4, 5)              \
  TK_SW(3, 4) TK_SW(2, 3) TK_SW(1, 2) TK_SW(0, 1)

__global__ __launch_bounds__(128, 4) void merge_kernel(
    const float* __restrict__ cd, const int* __restrict__ ci,
    int* __restrict__ idxf) {
  const int b = blockIdx.y;
  const int n = blockIdx.x * 128 + threadIdx.x;

  TK_LIST(TK_DECL)

  for (int ch = 0; ch < NCH; ++ch) {
    const size_t base = ((size_t)(b * NCH + ch) * KNN) * NN + n;
    for (int s = 0; s < KNN; ++s) {
      const float d = cd[base + (size_t)s * NN];
      const int j = ci[base + (size_t)s * NN];
      if ((d < td19) || ((d == td19) && (j < ti19))) {
        td19 = d;
        ti19 = j;
        TK_BUBBLE
      }
    }
  }

#define TK_STI(k) idxf[((size_t)b * KNN + (k)) * NN + n] = ti##k;
  TK_LIST(TK_STI)
#undef TK_STI
}

// ---------------------------------------------------------------------------
// Kernel 4: gather + max + leaky + transposed store (unchanged, bf16 A).
//   out[b][o][n] = leaky( Q[b][n][o] + max_k bf16(A)[b][idx[n][k]][o] )
// ---------------------------------------------------------------------------
__global__ __launch_bounds__(128) void gather_kernel(
    const unsigned short* __restrict__ Ab16, const float* __restrict__ Q,
    const int* __restrict__ idxf, float* __restrict__ out) {
  __shared__ int jidx[KNN][32];
  __shared__ float ob[32][OO + 1];

  const int b = blockIdx.y;
  const int n0 = blockIdx.x * 32;
  const int t = threadIdx.x;

  for (int e = t; e < KNN * 32; e += 128) {
    const int k = e >> 5, ii = e & 31;
    jidx[k][ii] = idxf[((size_t)b * KNN + k) * NN + n0 + ii];
  }
  __syncthreads();

  const unsigned short* Ab = Ab16 + (size_t)b * NN * OO;
  const float* Qb = Q + (size_t)b * NN * OO;

  for (int ii = 0; ii < 32; ++ii) {
    float m = -1e30f;
#pragma unroll
    for (int k = 0; k < KNN; ++k) {
      const unsigned v = Ab[(size_t)jidx[k][ii] * OO + t];  // coalesced 256B
      m = fmaxf(m, __uint_as_float(v << 16));
    }
    const float h = m + Qb[(size_t)(n0 + ii) * OO + t];
    ob[ii][t] = (h >= 0.f) ? h : 0.2f * h;
  }
  __syncthreads();

  float* ou = out + (size_t)b * OO * NN;
  for (int e = t; e < 32 * OO; e += 128) {
    const int ii = e & 31, oo = e >> 5;
    ou[(size_t)oo * NN + n0 + ii] = ob[ii][oo];
  }
}

// ---------------------------------------------------------------------------
extern "C" void kernel_launch(void* const* d_in, const int* in_sizes, int n_in,
                              void* d_out, int out_size, void* d_ws,
                              size_t ws_size, hipStream_t stream) {
  (void)in_sizes;
  (void)n_in;
  (void)out_size;
  (void)ws_size;
  const float* x = (const float*)d_in[0];
  const float* W = (const float*)d_in[1];
  const float* bias = (const float*)d_in[2];
  float* out = (float*)d_out;

  char* ws = (char*)d_ws;
  size_t off = 0;
  unsigned short* Ab16 = (unsigned short*)(ws + off);
  off += (size_t)BB * NN * OO * 2;              // 8 MB
  float* Q = (float*)(ws + off);
  off += (size_t)BB * NN * OO * 4;              // 16 MB
  float* xsq = (float*)(ws + off);
  off += (size_t)BB * NN * 4;                   // 128 KB
  unsigned short* xsp = (unsigned short*)(ws + off);
  off += (size_t)BB * NN * SPLITW * 2;          // 12.6 MB
  float* cd = (float*)(ws + off);
  off += (size_t)BB * NCH * KNN * NN * 4;       // 10.5 MB
  int* ci = (int*)(ws + off);
  off += (size_t)BB * NCH * KNN * NN * 4;       // 10.5 MB
  int* idxf = (int*)(ws + off);
  off += (size_t)BB * KNN * NN * 4;             // 2.6 MB

  precompute_kernel<<<dim3(NN / 128, BB), 128, 0, stream>>>(x, W, bias, Ab16,
                                                            Q, xsq, xsp);
  knn_kernel<<<dim3(NN / 64, BB), 256, 0, stream>>>(xsp, xsq, cd, ci);
  merge_kernel<<<dim3(NN / 128, BB), 128, 0, stream>>>(cd, ci, idxf);
  gather_kernel<<<dim3(NN / 32, BB), 128, 0, stream>>>(Ab16, Q, idxf, out);
}

// Round 16
// 733.257 us; speedup vs baseline: 1.2705x; 1.2705x over previous
//
#include <hip/hip_runtime.h>

#define BB 8
#define CC 64
#define OO 128
#define NN 4096
#define KNN 20
#define NT 256          // 16-j tiles per batch scan (full 4096 j)
#define NCH 4           // merge chunks = per-row col-classes (g)
#define RING 17         // per-lane LDS ring slots
#define TRIG 13         // drain when any lane cnt>=13 (growth <=4/tile -> <=16)
#define SPLITW 192      // xsp row: 64 bf16 h | 64 bf16 m | 64 bf16 l (384 B)
#define TILEB (16 * SPLITW * 2)  // 6144 B per 16-row B tile

typedef short bf16x8 __attribute__((ext_vector_type(8)));
typedef float f32x4 __attribute__((ext_vector_type(4)));
typedef const __attribute__((address_space(1))) unsigned int* gas_ptr;
typedef __attribute__((address_space(3))) unsigned int* las_ptr;

// ===========================================================================
// Top-20: UNSORTED slots + cached (kmax,kpos); kpos eviction + argmax tree.
// Proven R5-R15. NAMED SCALARS only (R2: no SROA).
// R15 lesson: naked per-tile barrier (no prefetch) serialized B-load latency
// -> 598us. R16: m97-pattern async global_load_lds staging: B tile (6KB,
// shared by all 4 waves) double-buffered in LDS via two SEPARATE __shared__
// arrays; stage(t+1) issued at half-iter top, lands during MFMA+select,
// barrier drains it. Zero VGPR cost (the R12 killer), 4x less B L2 traffic.
// Chunk-column-major swizzle (slot = m*16 + r) because global_load_lds
// cannot pad: contiguous rows would 8x-conflict the fragment ds_read_b128
// (bank = q*4+k for all 16 c-lanes); swizzled gives bank = c*4+k (free).
// ===========================================================================
#define REP20(F, P) F(P,0) F(P,1) F(P,2) F(P,3) F(P,4) F(P,5) F(P,6) F(P,7) \
    F(P,8) F(P,9) F(P,10) F(P,11) F(P,12) F(P,13) F(P,14) F(P,15) F(P,16)   \
    F(P,17) F(P,18) F(P,19)

#define TS_DECL(P,k) float P##m##k = 1e30f; int P##p##k = -1;
#define TS_REPL(P,k)                                                        \
  { const bool _h = (P##kpos == (k));                                       \
    P##m##k = _h ? _d : P##m##k;                                            \
    P##p##k = _h ? _j : P##p##k; }

#define TS_N(vd, xd, va, xa, vb, xb)                                        \
  { const bool _g = (vb) > (va); vd = _g ? (vb) : (va); xd = _g ? (xb) : (xa); }

#define TS_TREE(P)                                                          \
  { float t0,t1,t2,t3,t4,t5,t6,t7,t8,t9; int y0,y1,y2,y3,y4,y5,y6,y7,y8,y9; \
    TS_N(t0,y0, P##m0,0,  P##m1,1)   TS_N(t1,y1, P##m2,2,  P##m3,3)         \
    TS_N(t2,y2, P##m4,4,  P##m5,5)   TS_N(t3,y3, P##m6,6,  P##m7,7)         \
    TS_N(t4,y4, P##m8,8,  P##m9,9)   TS_N(t5,y5, P##m10,10, P##m11,11)      \
    TS_N(t6,y6, P##m12,12, P##m13,13) TS_N(t7,y7, P##m14,14, P##m15,15)     \
    TS_N(t8,y8, P##m16,16, P##m17,17) TS_N(t9,y9, P##m18,18, P##m19,19)     \
    float u0,u1,u2,u3,u4; int z0,z1,z2,z3,z4;                               \
    TS_N(u0,z0, t0,y0, t1,y1) TS_N(u1,z1, t2,y2, t3,y3)                     \
    TS_N(u2,z2, t4,y4, t5,y5) TS_N(u3,z3, t6,y6, t7,y7)                     \
    TS_N(u4,z4, t8,y8, t9,y9)                                               \
    float w0,w1; int q0,q1;                                                 \
    TS_N(w0,q0, u0,z0, u1,z1) TS_N(w1,q1, u2,z2, u3,z3)                     \
    float e0; int r0;                                                       \
    TS_N(e0,r0, w0,q0, w1,q1)                                               \
    TS_N(P##kmax, P##kpos, e0,r0, u4,z4) }

#define TS_INS(P, dval, jval)                                               \
  { const float _d = (dval); const int _j = (jval);                         \
    REP20(TS_REPL, P)                                                       \
    TS_TREE(P) }

// row-threshold refresh: rt = min(kmax over the 4 lanes sharing myrow)
#define RT_UPDATE                                                           \
  { const int _s1 = __builtin_amdgcn_ds_swizzle(__float_as_int(A_kmax), 0x101F); \
    const float _m1 = fminf(A_kmax, __int_as_float(_s1));                   \
    const int _s2 = __builtin_amdgcn_ds_swizzle(__float_as_int(_m1), 0x201F); \
    rt = fminf(_m1, __int_as_float(_s2)); }

__device__ __forceinline__ unsigned rne_bf16(float f) {
  const unsigned u = __float_as_uint(f);
  return (u + 0x7fffu + ((u >> 16) & 1u)) >> 16;
}

// ---------------------------------------------------------------------------
// Kernel 1: per-point precompute (unchanged from R14).
// ---------------------------------------------------------------------------
__global__ __launch_bounds__(128, 3) void precompute_kernel(
    const float* __restrict__ x, const float* __restrict__ W,
    const float* __restrict__ bias, unsigned short* __restrict__ Ab16,
    float* __restrict__ Q, float* __restrict__ xsq,
    unsigned short* __restrict__ xsp) {
  const int b = blockIdx.y;
  const int n = blockIdx.x * 128 + threadIdx.x;
  const float* xb = x + (size_t)b * CC * NN;

  float xr[CC];
  float sq = 0.f;
#pragma unroll
  for (int c = 0; c < CC; ++c) {
    xr[c] = xb[(size_t)c * NN + n];
    sq = fmaf(xr[c], xr[c], sq);
  }
  xsq[(size_t)b * NN + n] = sq;

  unsigned* srow = (unsigned*)(xsp + ((size_t)b * NN + n) * SPLITW);
#pragma unroll
  for (int c = 0; c < CC; c += 2) {
    const unsigned h0 = rne_bf16(xr[c]), h1 = rne_bf16(xr[c + 1]);
    const float r0 = xr[c] - __uint_as_float(h0 << 16);
    const float r1 = xr[c + 1] - __uint_as_float(h1 << 16);
    const unsigned m0 = rne_bf16(r0), m1 = rne_bf16(r1);
    const float s0 = r0 - __uint_as_float(m0 << 16);
    const float s1 = r1 - __uint_as_float(m1 << 16);
    const unsigned l0 = rne_bf16(s0), l1 = rne_bf16(s1);
    srow[c / 2] = h0 | (h1 << 16);
    srow[32 + c / 2] = m0 | (m1 << 16);
    srow[64 + c / 2] = l0 | (l1 << 16);
  }

  unsigned short* Arow = Ab16 + ((size_t)b * NN + n) * OO;
  float* Qrow = Q + ((size_t)b * NN + n) * OO;

  for (int og = 0; og < OO; og += 4) {
    float p[4] = {0.f, 0.f, 0.f, 0.f};
    float g[4] = {0.f, 0.f, 0.f, 0.f};
#pragma unroll
    for (int oo = 0; oo < 4; ++oo) {
      const float* wr = W + (size_t)(og + oo) * (2 * CC);
#pragma unroll
      for (int c = 0; c < CC; c += 4) {
        float4 w1 = *(const float4*)(wr + c);
        float4 w2 = *(const float4*)(wr + CC + c);
        p[oo] = fmaf(w1.x, xr[c], p[oo]);
        p[oo] = fmaf(w1.y, xr[c + 1], p[oo]);
        p[oo] = fmaf(w1.z, xr[c + 2], p[oo]);
        p[oo] = fmaf(w1.w, xr[c + 3], p[oo]);
        g[oo] = fmaf(w2.x, xr[c], g[oo]);
        g[oo] = fmaf(w2.y, xr[c + 1], g[oo]);
        g[oo] = fmaf(w2.z, xr[c + 2], g[oo]);
        g[oo] = fmaf(w2.w, xr[c + 3], g[oo]);
      }
    }
    const unsigned pa0 = rne_bf16(p[0]) | (rne_bf16(p[1]) << 16);
    const unsigned pa1 = rne_bf16(p[2]) | (rne_bf16(p[3]) << 16);
    *(uint2*)(Arow + og) = make_uint2(pa0, pa1);
    float4 qv = make_float4(g[0] - p[0] + bias[og + 0], g[1] - p[1] + bias[og + 1],
                            g[2] - p[2] + bias[og + 2], g[3] - p[3] + bias[og + 3]);
    *(float4*)(Qrow + og) = qv;
  }
}

// ---------------------------------------------------------------------------
// Kernel 2: MFMA Gram-matrix kNN with async LDS B-staging (m97 pattern).
// ---------------------------------------------------------------------------
// stage tile T's 6KB into BUFPTR, swizzled chunk-column-major: the 16B chunk
// (row r, idx m) lands at LDS slot m*16+r. 6 wave-instructions, split:
// wave 0: i=0,4; wave 1: i=1,5; wave 2: i=2; wave 3: i=3.
#define STAGE(T, BUFPTR)                                                    \
  { const char* tb = (const char*)xspB + (size_t)(T) * TILEB;               \
    __builtin_amdgcn_global_load_lds(                                       \
        (gas_ptr)(const void*)(tb + goff0),                                 \
        (las_ptr)(void*)((char*)(BUFPTR) + ldso0), 4, 0, 0);                \
    if (wv < 2)                                                             \
      __builtin_amdgcn_global_load_lds(                                     \
          (gas_ptr)(const void*)(tb + goff1),                               \
          (las_ptr)(void*)((char*)(BUFPTR) + ldso1), 4, 0, 0); }

// fragment reads from swizzled LDS: chunk m = q + 4*o at byte m*256 + c*16
#define TILE_MFMA_L(LBUF, BUF)                                              \
  { const char* bb = (const char*)(LBUF) + c16;                             \
    const bf16x8 Bh0 = *(const bf16x8*)(bb + (q + 0) * 256);                \
    const bf16x8 Bh1 = *(const bf16x8*)(bb + (q + 4) * 256);                \
    const bf16x8 Bm0 = *(const bf16x8*)(bb + (q + 8) * 256);                \
    const bf16x8 Bm1 = *(const bf16x8*)(bb + (q + 12) * 256);               \
    const bf16x8 Bl0 = *(const bf16x8*)(bb + (q + 16) * 256);               \
    const bf16x8 Bl1 = *(const bf16x8*)(bb + (q + 20) * 256);               \
    f32x4 ac0 = {0.f, 0.f, 0.f, 0.f};                                       \
    f32x4 ac1 = {0.f, 0.f, 0.f, 0.f};                                       \
    f32x4 ac2 = {0.f, 0.f, 0.f, 0.f};                                       \
    f32x4 ac3 = {0.f, 0.f, 0.f, 0.f};                                       \
    ac0 = __builtin_amdgcn_mfma_f32_16x16x32_bf16(Ah0, Bh0, ac0, 0, 0, 0);  \
    ac1 = __builtin_amdgcn_mfma_f32_16x16x32_bf16(Ah1, Bh1, ac1, 0, 0, 0);  \
    ac2 = __builtin_amdgcn_mfma_f32_16x16x32_bf16(Ah0, Bm0, ac2, 0, 0, 0);  \
    ac3 = __builtin_amdgcn_mfma_f32_16x16x32_bf16(Ah1, Bm1, ac3, 0, 0, 0);  \
    ac0 = __builtin_amdgcn_mfma_f32_16x16x32_bf16(Am0, Bh0, ac0, 0, 0, 0);  \
    ac1 = __builtin_amdgcn_mfma_f32_16x16x32_bf16(Am1, Bh1, ac1, 0, 0, 0);  \
    ac2 = __builtin_amdgcn_mfma_f32_16x16x32_bf16(Ah0, Bl0, ac2, 0, 0, 0);  \
    ac3 = __builtin_amdgcn_mfma_f32_16x16x32_bf16(Ah1, Bl1, ac3, 0, 0, 0);  \
    ac0 = __builtin_amdgcn_mfma_f32_16x16x32_bf16(Al0, Bh0, ac0, 0, 0, 0);  \
    ac1 = __builtin_amdgcn_mfma_f32_16x16x32_bf16(Al1, Bh1, ac1, 0, 0, 0);  \
    ac2 = __builtin_amdgcn_mfma_f32_16x16x32_bf16(Am0, Bm0, ac2, 0, 0, 0);  \
    ac3 = __builtin_amdgcn_mfma_f32_16x16x32_bf16(Am1, Bm1, ac3, 0, 0, 0);  \
    const f32x4 acc = (ac0 + ac1) + (ac2 + ac3);                            \
    float* bw = &bounce[BUF][wv][0];                                        \
    bw[(q * 4 + 0) * 20 + c] = acc[0];                                      \
    bw[(q * 4 + 1) * 20 + c] = acc[1];                                      \
    bw[(q * 4 + 2) * 20 + c] = acc[2];                                      \
    bw[(q * 4 + 3) * 20 + c] = acc[3]; }

#define TILE_VALS(T, BUF)                                                   \
  const float* br = &bounce[BUF][wv][myrow * 20 + 4 * g];                   \
  const f32x4 dots = *(const f32x4*)br;                                     \
  const float4 xx = *(const float4*)(xsqb + (T) * 16 + 4 * g);              \
  const float d0 = fmaf(-2.f, dots[0], xx.x);                               \
  const float d1 = fmaf(-2.f, dots[1], xx.y);                               \
  const float d2 = fmaf(-2.f, dots[2], xx.z);                               \
  const float d3 = fmaf(-2.f, dots[3], xx.w);                               \
  const int jb = (T) * 16 + 4 * g;

#define TILE_SELF(T, BUF, K0, K1, K2, K3)                                   \
  { TILE_VALS(T, BUF)                                                       \
    A_m##K0 = d0; A_p##K0 = jb;                                             \
    A_m##K1 = d1; A_p##K1 = jb + 1;                                         \
    A_m##K2 = d2; A_p##K2 = jb + 2;                                         \
    A_m##K3 = d3; A_p##K3 = jb + 3; }

#define TILE_SEL(T, BUF)                                                    \
  { TILE_VALS(T, BUF)                                                       \
    if (d0 <= rt) { myring[cnt] = make_float2(d0, __int_as_float(jb)); ++cnt; } \
    if (d1 <= rt) { myring[cnt] = make_float2(d1, __int_as_float(jb + 1)); ++cnt; } \
    if (d2 <= rt) { myring[cnt] = make_float2(d2, __int_as_float(jb + 2)); ++cnt; } \
    if (d3 <= rt) { myring[cnt] = make_float2(d3, __int_as_float(jb + 3)); ++cnt; } \
    if (__ballot(cnt >= TRIG)) {                                            \
      for (int _k = 0; _k < cnt; ++_k) {                                    \
        const float2 e = myring[_k];                                        \
        if (e.x < A_kmax) { TS_INS(A_, e.x, __float_as_int(e.y)) }          \
      }                                                                     \
      cnt = 0;                                                              \
    }                                                                       \
    RT_UPDATE }

__global__ __launch_bounds__(256, 2) void knn_kernel(
    const unsigned short* __restrict__ xsp, const float* __restrict__ xsq,
    float* __restrict__ cd, int* __restrict__ ci) {
  __shared__ unsigned short Bbuf0[TILEB / 2];  // 6 KB, swizzled B tile (even)
  __shared__ unsigned short Bbuf1[TILEB / 2];  // 6 KB (odd tiles)
  __shared__ float bounce[2][4][16 * 20];      // per-wave bounce, 10 KB
  __shared__ float2 ring[256][RING];           // 34 KB

  const int b = blockIdx.y;
  const int wv = threadIdx.x >> 6;
  const int lane = threadIdx.x & 63;
  const int q = lane >> 4;
  const int c = lane & 15;
  const int c16 = c * 16;
  const int ibase = blockIdx.x * 64 + wv * 16;
  const int myrow = q * 4 + (c & 3);
  const int g = c >> 2;
  const int isel = ibase + myrow;

  const unsigned short* xspB = xsp + (size_t)b * NN * SPLITW;
  const float* xsqb = xsq + (size_t)b * NN;

  // staging lane-offsets: instr i covers slots i*64+lane; slot s holds
  // global chunk (r = s&15, m = s>>4) at row-byte r*384 + m*16.
  // NOTE size=4: 4B per lane x 64 lanes... (16B chunks staged as 4 lanes?)
  // -> use 16B per lane: slot granularity 16B, instr covers 64 slots.
  const int s0 = wv * 64 + lane;
  const int goff0 = (s0 & 15) * (SPLITW * 2) + (s0 >> 4) * 16;
  const int ldso0 = s0 * 16 - wv * 64 * 16 + wv * 1024;  // = wv*1024 + lane*16 base handled by HW
  const int s1 = (wv + 4) * 64 + lane;
  const int goff1 = (s1 & 15) * (SPLITW * 2) + (s1 >> 4) * 16;
  const int ldso1 = (wv + 4) * 1024;

  // A fragments: rows ibase+c, k-slice quad*8 (+32 for k-chunk 1)
  const unsigned short* arow = xspB + (size_t)(ibase + c) * SPLITW + q * 8;
  const bf16x8 Ah0 = *(const bf16x8*)(arow);
  const bf16x8 Ah1 = *(const bf16x8*)(arow + 32);
  const bf16x8 Am0 = *(const bf16x8*)(arow + 64);
  const bf16x8 Am1 = *(const bf16x8*)(arow + 96);
  const bf16x8 Al0 = *(const bf16x8*)(arow + 128);
  const bf16x8 Al1 = *(const bf16x8*)(arow + 160);

  REP20(TS_DECL, A_)
  float A_kmax = 1e30f; int A_kpos = 0;
  float rt = 1e30f;
  float2* myring = ring[threadIdx.x];
  int cnt = 0;

  (void)ldso0;  // HW places lane data at ldsbase + lane*16; pass wv*1024 base
#undef STAGE
#define STAGE(T, BUFPTR)                                                    \
  { const char* tb = (const char*)xspB + (size_t)(T) * TILEB;               \
    __builtin_amdgcn_global_load_lds(                                       \
        (gas_ptr)(const void*)(tb + goff0),                                 \
        (las_ptr)(void*)((char*)(BUFPTR) + wv * 1024), 16, 0, 0);           \
    if (wv < 2)                                                             \
      __builtin_amdgcn_global_load_lds(                                     \
          (gas_ptr)(const void*)(tb + goff1),                               \
          (las_ptr)(void*)((char*)(BUFPTR) + ldso1), 16, 0, 0); }

  // ---- prologue: prime pipeline, direct-fill first 5 tiles ----
  STAGE(0, Bbuf0)
  __syncthreads();
  STAGE(1, Bbuf1) TILE_MFMA_L(Bbuf0, 0)
  __syncthreads();
  STAGE(2, Bbuf0) TILE_MFMA_L(Bbuf1, 1) TILE_SELF(0, 0, 0, 1, 2, 3)
  __syncthreads();
  STAGE(3, Bbuf1) TILE_MFMA_L(Bbuf0, 0) TILE_SELF(1, 1, 4, 5, 6, 7)
  __syncthreads();
  STAGE(4, Bbuf0) TILE_MFMA_L(Bbuf1, 1) TILE_SELF(2, 0, 8, 9, 10, 11)
  __syncthreads();
  STAGE(5, Bbuf1) TILE_MFMA_L(Bbuf0, 0) TILE_SELF(3, 1, 12, 13, 14, 15)
  __syncthreads();
  STAGE(6, Bbuf0) TILE_MFMA_L(Bbuf1, 1) TILE_SELF(4, 0, 16, 17, 18, 19)
  __syncthreads();
  TS_TREE(A_)
  RT_UPDATE

  // ---- steady state: stage(t+1) async, compute(t), select(t-1), barrier ----
  for (int t = 6; t < 252; t += 2) {
    STAGE(t + 1, Bbuf1) TILE_MFMA_L(Bbuf0, 0) TILE_SEL(t - 1, 1)
    __syncthreads();
    STAGE(t + 2, Bbuf0) TILE_MFMA_L(Bbuf1, 1) TILE_SEL(t, 0)
    __syncthreads();
  }
  // epilogue: tiles 252..255
  STAGE(253, Bbuf1) TILE_MFMA_L(Bbuf0, 0) TILE_SEL(251, 1)
  __syncthreads();
  STAGE(254, Bbuf0) TILE_MFMA_L(Bbuf1, 1) TILE_SEL(252, 0)
  __syncthreads();
  STAGE(255, Bbuf1) TILE_MFMA_L(Bbuf0, 0) TILE_SEL(253, 1)
  __syncthreads();
  TILE_MFMA_L(Bbuf1, 1) TILE_SEL(254, 0)
  TILE_SEL(255, 1)

  // final drain
  for (int _k = 0; _k < cnt; ++_k) {
    const float2 e = myring[_k];
    if (e.x < A_kmax) { TS_INS(A_, e.x, __float_as_int(e.y)) }
  }

  const size_t base = ((size_t)(b * NCH + g) * KNN) * NN + isel;
#define TS_ST(P,k) cd[base + (size_t)(k) * NN] = P##m##k; \
                   ci[base + (size_t)(k) * NN] = P##p##k;
  REP20(TS_ST, A_)
#undef TS_ST
}

// ---------------------------------------------------------------------------
// Kernel 3: merge NCH=4 unsorted 20-lists (lex (d, j) compare — exact jax).
// ---------------------------------------------------------------------------
#define TK_LIST(OP) OP(0) OP(1) OP(2) OP(3) OP(4) OP(5) OP(6) OP(7) OP(8) \
    OP(9) OP(10) OP(11) OP(12) OP(13) OP(14) OP(15) OP(16) OP(17) OP(18) OP(19)
#define TK_DECL(k) float td##k = 1e30f; int ti##k = -1;
#define TK_SW(a, b)                                                        \
  {                                                                        \
    const bool _s = (td##b < td##a) ||                                     \
                    ((td##b == td##a) && (ti##b < ti##a));                 \
    const float _fa = _s ? td##b : td##a;                                  \
    const float _fb = _s ? td##a : td##b;                                  \
    const int _ia = _s ? ti##b : ti##a;                                    \
    const int _ib = _s ? ti##a : ti##b;                                    \
    td##a = _fa; td##b = _fb; ti##a = _ia; ti##b = _ib;                    \
  }
#define TK_BUBBLE                                                          \
  TK_SW(18, 19) TK_SW(17, 18) TK_SW(16, 17) TK_SW(15, 16) TK_SW(14, 15)    \
  TK_SW(13, 14) TK_SW(12, 13) TK_SW(11, 12) TK_SW(10, 11) TK_SW(9, 10)     \
  TK_SW(8, 9) TK_SW(7, 8) TK_SW(6, 7) TK_SW(5, 6) TK_SW(4, 5)              \
  TK_SW(3, 4) TK_SW(2, 3) TK_SW(1, 2) TK_SW(0, 1)

__global__ __launch_bounds__(128, 4) void merge_kernel(
    const float* __restrict__ cd, const int* __restrict__ ci,
    int* __restrict__ idxf) {
  const int b = blockIdx.y;
  const int n = blockIdx.x * 128 + threadIdx.x;

  TK_LIST(TK_DECL)

  for (int ch = 0; ch < NCH; ++ch) {
    const size_t base = ((size_t)(b * NCH + ch) * KNN) * NN + n;
    for (int s = 0; s < KNN; ++s) {
      const float d = cd[base + (size_t)s * NN];
      const int j = ci[base + (size_t)s * NN];
      if ((d < td19) || ((d == td19) && (j < ti19))) {
        td19 = d;
        ti19 = j;
        TK_BUBBLE
      }
    }
  }

#define TK_STI(k) idxf[((size_t)b * KNN + (k)) * NN + n] = ti##k;
  TK_LIST(TK_STI)
#undef TK_STI
}

// ---------------------------------------------------------------------------
// Kernel 4: gather + max + leaky + transposed store (bf16 A).
// ---------------------------------------------------------------------------
__global__ __launch_bounds__(128) void gather_kernel(
    const unsigned short* __restrict__ Ab16, const float* __restrict__ Q,
    const int* __restrict__ idxf, float* __restrict__ out) {
  __shared__ int jidx[KNN][32];
  __shared__ float ob[32][OO + 1];

  const int b = blockIdx.y;
  const int n0 = blockIdx.x * 32;
  const int t = threadIdx.x;

  for (int e = t; e < KNN * 32; e += 128) {
    const int k = e >> 5, ii = e & 31;
    jidx[k][ii] = idxf[((size_t)b * KNN + k) * NN + n0 + ii];
  }
  __syncthreads();

  const unsigned short* Ab = Ab16 + (size_t)b * NN * OO;
  const float* Qb = Q + (size_t)b * NN * OO;

  for (int ii = 0; ii < 32; ++ii) {
    float m = -1e30f;
#pragma unroll
    for (int k = 0; k < KNN; ++k) {
      const unsigned v = Ab[(size_t)jidx[k][ii] * OO + t];
      m = fmaxf(m, __uint_as_float(v << 16));
    }
    const float h = m + Qb[(size_t)(n0 + ii) * OO + t];
    ob[ii][t] = (h >= 0.f) ? h : 0.2f * h;
  }
  __syncthreads();

  float* ou = out + (size_t)b * OO * NN;
  for (int e = t; e < 32 * OO; e += 128) {
    const int ii = e & 31, oo = e >> 5;
    ou[(size_t)oo * NN + n0 + ii] = ob[ii][oo];
  }
}

// ---------------------------------------------------------------------------
extern "C" void kernel_launch(void* const* d_in, const int* in_sizes, int n_in,
                              void* d_out, int out_size, void* d_ws,
                              size_t ws_size, hipStream_t stream) {
  (void)in_sizes;
  (void)n_in;
  (void)out_size;
  (void)ws_size;
  const float* x = (const float*)d_in[0];
  const float* W = (const float*)d_in[1];
  const float* bias = (const float*)d_in[2];
  float* out = (float*)d_out;

  char* ws = (char*)d_ws;
  size_t off = 0;
  unsigned short* Ab16 = (unsigned short*)(ws + off);
  off += (size_t)BB * NN * OO * 2;              // 8 MB
  float* Q = (float*)(ws + off);
  off += (size_t)BB * NN * OO * 4;              // 16 MB
  float* xsq = (float*)(ws + off);
  off += (size_t)BB * NN * 4;                   // 128 KB
  unsigned short* xsp = (unsigned short*)(ws + off);
  off += (size_t)BB * NN * SPLITW * 2;          // 12.6 MB
  float* cd = (float*)(ws + off);
  off += (size_t)BB * NCH * KNN * NN * 4;       // 10.5 MB
  int* ci = (int*)(ws + off);
  off += (size_t)BB * NCH * KNN * NN * 4;       // 10.5 MB
  int* idxf = (int*)(ws + off);
  off += (size_t)BB * KNN * NN * 4;             // 2.6 MB

  precompute_kernel<<<dim3(NN / 128, BB), 128, 0, stream>>>(x, W, bias, Ab16,
                                                            Q, xsq, xsp);
  knn_kernel<<<dim3(NN / 64, BB), 256, 0, stream>>>(xsp, xsq, cd, ci);
  merge_kernel<<<dim3(NN / 128, BB), 128, 0, stream>>>(cd, ci, idxf);
  gather_kernel<<<dim3(NN / 32, BB), 128, 0, stream>>>(Ab16, Q, idxf, out);
}

// Round 17
// 690.553 us; speedup vs baseline: 1.3491x; 1.0618x over previous
//
#include <hip/hip_runtime.h>

#define BB 8
#define CC 64
#define OO 128
#define NN 4096
#define KNN 20
#define NT 256          // 16-j tiles per batch scan
#define NG 64           // 4-tile groups
#define NCH 4           // merge chunks = per-row col-classes (g)
#define RING 9          // per-lane LDS ring slots
#define TRIG 5          // drain when any lane cnt>=5 (growth <=4/tile -> <=8)
#define SPLITW 192      // xsp row: 64 bf16 h | 64 bf16 m | 64 bf16 l (384 B)
#define TILEB (16 * SPLITW * 2)  // 6144 B per 16-row B tile

typedef short bf16x8 __attribute__((ext_vector_type(8)));
typedef float f32x4 __attribute__((ext_vector_type(4)));
typedef const __attribute__((address_space(1))) unsigned int* gas_ptr;
typedef __attribute__((address_space(3))) unsigned int* las_ptr;

// ===========================================================================
// Top-20: UNSORTED slots + cached (kmax,kpos); kpos eviction + argmax tree.
// Proven R5-R16. NAMED SCALARS only (R2: no SROA).
// R16 lesson: per-tile __syncthreads drains vmcnt(0) -> staging of t+1 must
// COMPLETE at every tile barrier with only ~250cyc of compute since issue;
// per-wave-tile stayed ~1840cyc. R17: 4-tile groups per barrier (24KB
// staged, double-buffered) -> barriers 256->65, staging has ~4x compute to
// land. Ring 17->9 / TRIG 5 to fit 2 blocks/CU (76KB LDS).
// ===========================================================================
#define REP20(F, P) F(P,0) F(P,1) F(P,2) F(P,3) F(P,4) F(P,5) F(P,6) F(P,7) \
    F(P,8) F(P,9) F(P,10) F(P,11) F(P,12) F(P,13) F(P,14) F(P,15) F(P,16)   \
    F(P,17) F(P,18) F(P,19)

#define TS_DECL(P,k) float P##m##k = 1e30f; int P##p##k = -1;
#define TS_REPL(P,k)                                                        \
  { const bool _h = (P##kpos == (k));                                       \
    P##m##k = _h ? _d : P##m##k;                                            \
    P##p##k = _h ? _j : P##p##k; }

#define TS_N(vd, xd, va, xa, vb, xb)                                        \
  { const bool _g = (vb) > (va); vd = _g ? (vb) : (va); xd = _g ? (xb) : (xa); }

#define TS_TREE(P)                                                          \
  { float t0,t1,t2,t3,t4,t5,t6,t7,t8,t9; int y0,y1,y2,y3,y4,y5,y6,y7,y8,y9; \
    TS_N(t0,y0, P##m0,0,  P##m1,1)   TS_N(t1,y1, P##m2,2,  P##m3,3)         \
    TS_N(t2,y2, P##m4,4,  P##m5,5)   TS_N(t3,y3, P##m6,6,  P##m7,7)         \
    TS_N(t4,y4, P##m8,8,  P##m9,9)   TS_N(t5,y5, P##m10,10, P##m11,11)      \
    TS_N(t6,y6, P##m12,12, P##m13,13) TS_N(t7,y7, P##m14,14, P##m15,15)     \
    TS_N(t8,y8, P##m16,16, P##m17,17) TS_N(t9,y9, P##m18,18, P##m19,19)     \
    float u0,u1,u2,u3,u4; int z0,z1,z2,z3,z4;                               \
    TS_N(u0,z0, t0,y0, t1,y1) TS_N(u1,z1, t2,y2, t3,y3)                     \
    TS_N(u2,z2, t4,y4, t5,y5) TS_N(u3,z3, t6,y6, t7,y7)                     \
    TS_N(u4,z4, t8,y8, t9,y9)                                               \
    float w0,w1; int q0,q1;                                                 \
    TS_N(w0,q0, u0,z0, u1,z1) TS_N(w1,q1, u2,z2, u3,z3)                     \
    float e0; int r0;                                                       \
    TS_N(e0,r0, w0,q0, w1,q1)                                               \
    TS_N(P##kmax, P##kpos, e0,r0, u4,z4) }

#define TS_INS(P, dval, jval)                                               \
  { const float _d = (dval); const int _j = (jval);                         \
    REP20(TS_REPL, P)                                                       \
    TS_TREE(P) }

// row-threshold refresh: rt = min(kmax over the 4 lanes sharing myrow)
#define RT_UPDATE                                                           \
  { const int _s1 = __builtin_amdgcn_ds_swizzle(__float_as_int(A_kmax), 0x101F); \
    const float _m1 = fminf(A_kmax, __int_as_float(_s1));                   \
    const int _s2 = __builtin_amdgcn_ds_swizzle(__float_as_int(_m1), 0x201F); \
    rt = fminf(_m1, __int_as_float(_s2)); }

__device__ __forceinline__ unsigned rne_bf16(float f) {
  const unsigned u = __float_as_uint(f);
  return (u + 0x7fffu + ((u >> 16) & 1u)) >> 16;
}

// ---------------------------------------------------------------------------
// Kernel 1: per-point precompute (unchanged from R14).
// ---------------------------------------------------------------------------
__global__ __launch_bounds__(128, 3) void precompute_kernel(
    const float* __restrict__ x, const float* __restrict__ W,
    const float* __restrict__ bias, unsigned short* __restrict__ Ab16,
    float* __restrict__ Q, float* __restrict__ xsq,
    unsigned short* __restrict__ xsp) {
  const int b = blockIdx.y;
  const int n = blockIdx.x * 128 + threadIdx.x;
  const float* xb = x + (size_t)b * CC * NN;

  float xr[CC];
  float sq = 0.f;
#pragma unroll
  for (int c = 0; c < CC; ++c) {
    xr[c] = xb[(size_t)c * NN + n];
    sq = fmaf(xr[c], xr[c], sq);
  }
  xsq[(size_t)b * NN + n] = sq;

  unsigned* srow = (unsigned*)(xsp + ((size_t)b * NN + n) * SPLITW);
#pragma unroll
  for (int c = 0; c < CC; c += 2) {
    const unsigned h0 = rne_bf16(xr[c]), h1 = rne_bf16(xr[c + 1]);
    const float r0 = xr[c] - __uint_as_float(h0 << 16);
    const float r1 = xr[c + 1] - __uint_as_float(h1 << 16);
    const unsigned m0 = rne_bf16(r0), m1 = rne_bf16(r1);
    const float s0 = r0 - __uint_as_float(m0 << 16);
    const float s1 = r1 - __uint_as_float(m1 << 16);
    const unsigned l0 = rne_bf16(s0), l1 = rne_bf16(s1);
    srow[c / 2] = h0 | (h1 << 16);
    srow[32 + c / 2] = m0 | (m1 << 16);
    srow[64 + c / 2] = l0 | (l1 << 16);
  }

  unsigned short* Arow = Ab16 + ((size_t)b * NN + n) * OO;
  float* Qrow = Q + ((size_t)b * NN + n) * OO;

  for (int og = 0; og < OO; og += 4) {
    float p[4] = {0.f, 0.f, 0.f, 0.f};
    float g[4] = {0.f, 0.f, 0.f, 0.f};
#pragma unroll
    for (int oo = 0; oo < 4; ++oo) {
      const float* wr = W + (size_t)(og + oo) * (2 * CC);
#pragma unroll
      for (int c = 0; c < CC; c += 4) {
        float4 w1 = *(const float4*)(wr + c);
        float4 w2 = *(const float4*)(wr + CC + c);
        p[oo] = fmaf(w1.x, xr[c], p[oo]);
        p[oo] = fmaf(w1.y, xr[c + 1], p[oo]);
        p[oo] = fmaf(w1.z, xr[c + 2], p[oo]);
        p[oo] = fmaf(w1.w, xr[c + 3], p[oo]);
        g[oo] = fmaf(w2.x, xr[c], g[oo]);
        g[oo] = fmaf(w2.y, xr[c + 1], g[oo]);
        g[oo] = fmaf(w2.z, xr[c + 2], g[oo]);
        g[oo] = fmaf(w2.w, xr[c + 3], g[oo]);
      }
    }
    const unsigned pa0 = rne_bf16(p[0]) | (rne_bf16(p[1]) << 16);
    const unsigned pa1 = rne_bf16(p[2]) | (rne_bf16(p[3]) << 16);
    *(uint2*)(Arow + og) = make_uint2(pa0, pa1);
    float4 qv = make_float4(g[0] - p[0] + bias[og + 0], g[1] - p[1] + bias[og + 1],
                            g[2] - p[2] + bias[og + 2], g[3] - p[3] + bias[og + 3]);
    *(float4*)(Qrow + og) = qv;
  }
}

// ---------------------------------------------------------------------------
// Kernel 2: MFMA Gram-matrix kNN, 4-tile-group async staging.
// Wave wv stages tile 4G+wv (6 x global_load_lds, 16B/lane). Swizzle: LDS
// slot s = k*64+lane holds global chunk at c*384 + q*16 + k*64 (proven R16
// mapping: slot = m*16 + r, bank = c*4+k, conflict-free fragment reads).
// ---------------------------------------------------------------------------
#define STAGEG(G, BUF)                                                      \
  { const char* tb = (const char*)xspB + (size_t)(4 * (G) + wv) * TILEB + gof; \
    char* lb = (char*)(BUF) + wv * 6144;                                    \
    __builtin_amdgcn_global_load_lds((gas_ptr)(const void*)(tb), (las_ptr)(void*)(lb), 16, 0, 0); \
    __builtin_amdgcn_global_load_lds((gas_ptr)(const void*)(tb + 64), (las_ptr)(void*)(lb + 1024), 16, 0, 0); \
    __builtin_amdgcn_global_load_lds((gas_ptr)(const void*)(tb + 128), (las_ptr)(void*)(lb + 2048), 16, 0, 0); \
    __builtin_amdgcn_global_load_lds((gas_ptr)(const void*)(tb + 192), (las_ptr)(void*)(lb + 3072), 16, 0, 0); \
    __builtin_amdgcn_global_load_lds((gas_ptr)(const void*)(tb + 256), (las_ptr)(void*)(lb + 4096), 16, 0, 0); \
    __builtin_amdgcn_global_load_lds((gas_ptr)(const void*)(tb + 320), (las_ptr)(void*)(lb + 5120), 16, 0, 0); }

// fragment reads from swizzled LDS: chunk m = q+4*o at byte m*256 + c*16
#define TILE_MFMA_L(LBUF, BUF)                                              \
  { const char* bb = (const char*)(LBUF) + c16;                             \
    const bf16x8 Bh0 = *(const bf16x8*)(bb + (q + 0) * 256);                \
    const bf16x8 Bh1 = *(const bf16x8*)(bb + (q + 4) * 256);                \
    const bf16x8 Bm0 = *(const bf16x8*)(bb + (q + 8) * 256);                \
    const bf16x8 Bm1 = *(const bf16x8*)(bb + (q + 12) * 256);               \
    const bf16x8 Bl0 = *(const bf16x8*)(bb + (q + 16) * 256);               \
    const bf16x8 Bl1 = *(const bf16x8*)(bb + (q + 20) * 256);               \
    f32x4 ac0 = {0.f, 0.f, 0.f, 0.f};                                       \
    f32x4 ac1 = {0.f, 0.f, 0.f, 0.f};                                       \
    f32x4 ac2 = {0.f, 0.f, 0.f, 0.f};                                       \
    f32x4 ac3 = {0.f, 0.f, 0.f, 0.f};                                       \
    ac0 = __builtin_amdgcn_mfma_f32_16x16x32_bf16(Ah0, Bh0, ac0, 0, 0, 0);  \
    ac1 = __builtin_amdgcn_mfma_f32_16x16x32_bf16(Ah1, Bh1, ac1, 0, 0, 0);  \
    ac2 = __builtin_amdgcn_mfma_f32_16x16x32_bf16(Ah0, Bm0, ac2, 0, 0, 0);  \
    ac3 = __builtin_amdgcn_mfma_f32_16x16x32_bf16(Ah1, Bm1, ac3, 0, 0, 0);  \
    ac0 = __builtin_amdgcn_mfma_f32_16x16x32_bf16(Am0, Bh0, ac0, 0, 0, 0);  \
    ac1 = __builtin_amdgcn_mfma_f32_16x16x32_bf16(Am1, Bh1, ac1, 0, 0, 0);  \
    ac2 = __builtin_amdgcn_mfma_f32_16x16x32_bf16(Ah0, Bl0, ac2, 0, 0, 0);  \
    ac3 = __builtin_amdgcn_mfma_f32_16x16x32_bf16(Ah1, Bl1, ac3, 0, 0, 0);  \
    ac0 = __builtin_amdgcn_mfma_f32_16x16x32_bf16(Al0, Bh0, ac0, 0, 0, 0);  \
    ac1 = __builtin_amdgcn_mfma_f32_16x16x32_bf16(Al1, Bh1, ac1, 0, 0, 0);  \
    ac2 = __builtin_amdgcn_mfma_f32_16x16x32_bf16(Am0, Bm0, ac2, 0, 0, 0);  \
    ac3 = __builtin_amdgcn_mfma_f32_16x16x32_bf16(Am1, Bm1, ac3, 0, 0, 0);  \
    const f32x4 acc = (ac0 + ac1) + (ac2 + ac3);                            \
    float* bw = &bounce[BUF][wv][0];                                        \
    bw[(q * 4 + 0) * 20 + c] = acc[0];                                      \
    bw[(q * 4 + 1) * 20 + c] = acc[1];                                      \
    bw[(q * 4 + 2) * 20 + c] = acc[2];                                      \
    bw[(q * 4 + 3) * 20 + c] = acc[3]; }

#define TILE_VALS(T, BUF)                                                   \
  const float* br = &bounce[BUF][wv][myrow * 20 + 4 * g];                   \
  const f32x4 dots = *(const f32x4*)br;                                     \
  const float4 xx = *(const float4*)(xsqb + (T) * 16 + 4 * g);              \
  const float d0 = fmaf(-2.f, dots[0], xx.x);                               \
  const float d1 = fmaf(-2.f, dots[1], xx.y);                               \
  const float d2 = fmaf(-2.f, dots[2], xx.z);                               \
  const float d3 = fmaf(-2.f, dots[3], xx.w);                               \
  const int jb = (T) * 16 + 4 * g;

#define TILE_SELF(T, BUF, K0, K1, K2, K3)                                   \
  { TILE_VALS(T, BUF)                                                       \
    A_m##K0 = d0; A_p##K0 = jb;                                             \
    A_m##K1 = d1; A_p##K1 = jb + 1;                                         \
    A_m##K2 = d2; A_p##K2 = jb + 2;                                         \
    A_m##K3 = d3; A_p##K3 = jb + 3; }

#define TILE_SEL(T, BUF)                                                    \
  { TILE_VALS(T, BUF)                                                       \
    if (d0 <= rt) { myring[cnt] = make_float2(d0, __int_as_float(jb)); ++cnt; } \
    if (d1 <= rt) { myring[cnt] = make_float2(d1, __int_as_float(jb + 1)); ++cnt; } \
    if (d2 <= rt) { myring[cnt] = make_float2(d2, __int_as_float(jb + 2)); ++cnt; } \
    if (d3 <= rt) { myring[cnt] = make_float2(d3, __int_as_float(jb + 3)); ++cnt; } \
    if (__ballot(cnt >= TRIG)) {                                            \
      for (int _k = 0; _k < cnt; ++_k) {                                    \
        const float2 e = myring[_k];                                        \
        if (e.x < A_kmax) { TS_INS(A_, e.x, __float_as_int(e.y)) }          \
      }                                                                     \
      cnt = 0;                                                              \
    }                                                                       \
    RT_UPDATE }

__global__ __launch_bounds__(256, 2) void knn_kernel(
    const unsigned short* __restrict__ xsp, const float* __restrict__ xsq,
    float* __restrict__ cd, int* __restrict__ ci) {
  __shared__ unsigned short Bbuf0[4 * TILEB / 2];  // 24 KB (even groups)
  __shared__ unsigned short Bbuf1[4 * TILEB / 2];  // 24 KB (odd groups)
  __shared__ float bounce[2][4][16 * 20];          // 10 KB
  __shared__ float2 ring[256][RING];               // 18 KB

  const int b = blockIdx.y;
  const int wv = threadIdx.x >> 6;
  const int lane = threadIdx.x & 63;
  const int q = lane >> 4;
  const int c = lane & 15;
  const int c16 = c * 16;
  const int gof = c * 384 + q * 16;  // staging source offset (k adds 64)
  const int ibase = blockIdx.x * 64 + wv * 16;
  const int myrow = q * 4 + (c & 3);
  const int g = c >> 2;
  const int isel = ibase + myrow;

  const unsigned short* xspB = xsp + (size_t)b * NN * SPLITW;
  const float* xsqb = xsq + (size_t)b * NN;

  // A fragments: rows ibase+c, k-slice quad*8 (+32 for k-chunk 1)
  const unsigned short* arow = xspB + (size_t)(ibase + c) * SPLITW + q * 8;
  const bf16x8 Ah0 = *(const bf16x8*)(arow);
  const bf16x8 Ah1 = *(const bf16x8*)(arow + 32);
  const bf16x8 Am0 = *(const bf16x8*)(arow + 64);
  const bf16x8 Am1 = *(const bf16x8*)(arow + 96);
  const bf16x8 Al0 = *(const bf16x8*)(arow + 128);
  const bf16x8 Al1 = *(const bf16x8*)(arow + 160);

  REP20(TS_DECL, A_)
  float A_kmax = 1e30f; int A_kpos = 0;
  float rt = 1e30f;
  float2* myring = ring[threadIdx.x];
  int cnt = 0;

  // ---- prologue ----
  STAGEG(0, Bbuf0)
  __syncthreads();
  // group 0: tiles 0..3 from Bbuf0; stage group 1
  STAGEG(1, Bbuf1)
  TILE_MFMA_L(Bbuf0 + 0 * 3072, 0)
  TILE_MFMA_L(Bbuf0 + 1 * 3072, 1) TILE_SELF(0, 0, 0, 1, 2, 3)
  TILE_MFMA_L(Bbuf0 + 2 * 3072, 0) TILE_SELF(1, 1, 4, 5, 6, 7)
  TILE_MFMA_L(Bbuf0 + 3 * 3072, 1) TILE_SELF(2, 0, 8, 9, 10, 11)
  __syncthreads();
  // group 1: tiles 4..7 from Bbuf1; stage group 2
  STAGEG(2, Bbuf0)
  TILE_MFMA_L(Bbuf1 + 0 * 3072, 0) TILE_SELF(3, 1, 12, 13, 14, 15)
  TILE_MFMA_L(Bbuf1 + 1 * 3072, 1) TILE_SELF(4, 0, 16, 17, 18, 19)
  TS_TREE(A_)
  RT_UPDATE
  TILE_MFMA_L(Bbuf1 + 2 * 3072, 0) TILE_SEL(5, 1)
  TILE_MFMA_L(Bbuf1 + 3 * 3072, 1) TILE_SEL(6, 0)
  __syncthreads();

  // ---- steady state: groups 2..62 ----
  for (int G = 2; G < NG - 1; ++G) {
    unsigned short* cur = (G & 1) ? Bbuf1 : Bbuf0;
    unsigned short* nxt = (G & 1) ? Bbuf0 : Bbuf1;
    STAGEG(G + 1, nxt)
    const int t0 = 4 * G;
    TILE_MFMA_L(cur + 0 * 3072, 0) TILE_SEL(t0 - 1, 1)
    TILE_MFMA_L(cur + 1 * 3072, 1) TILE_SEL(t0, 0)
    TILE_MFMA_L(cur + 2 * 3072, 0) TILE_SEL(t0 + 1, 1)
    TILE_MFMA_L(cur + 3 * 3072, 1) TILE_SEL(t0 + 2, 0)
    __syncthreads();
  }

  // ---- epilogue: group 63 (tiles 252..255 in Bbuf1), no staging ----
  TILE_MFMA_L(Bbuf1 + 0 * 3072, 0) TILE_SEL(251, 1)
  TILE_MFMA_L(Bbuf1 + 1 * 3072, 1) TILE_SEL(252, 0)
  TILE_MFMA_L(Bbuf1 + 2 * 3072, 0) TILE_SEL(253, 1)
  TILE_MFMA_L(Bbuf1 + 3 * 3072, 1) TILE_SEL(254, 0)
  TILE_SEL(255, 1)

  // final drain
  for (int _k = 0; _k < cnt; ++_k) {
    const float2 e = myring[_k];
    if (e.x < A_kmax) { TS_INS(A_, e.x, __float_as_int(e.y)) }
  }

  const size_t base = ((size_t)(b * NCH + g) * KNN) * NN + isel;
#define TS_ST(P,k) cd[base + (size_t)(k) * NN] = P##m##k; \
                   ci[base + (size_t)(k) * NN] = P##p##k;
  REP20(TS_ST, A_)
#undef TS_ST
}

// ---------------------------------------------------------------------------
// Kernel 3: merge NCH=4 unsorted 20-lists (lex (d, j) compare — exact jax).
// ---------------------------------------------------------------------------
#define TK_LIST(OP) OP(0) OP(1) OP(2) OP(3) OP(4) OP(5) OP(6) OP(7) OP(8) \
    OP(9) OP(10) OP(11) OP(12) OP(13) OP(14) OP(15) OP(16) OP(17) OP(18) OP(19)
#define TK_DECL(k) float td##k = 1e30f; int ti##k = -1;
#define TK_SW(a, b)                                                        \
  {                                                                        \
    const bool _s = (td##b < td##a) ||                                     \
                    ((td##b == td##a) && (ti##b < ti##a));                 \
    const float _fa = _s ? td##b : td##a;                                  \
    const float _fb = _s ? td##a : td##b;                                  \
    const int _ia = _s ? ti##b : ti##a;                                    \
    const int _ib = _s ? ti##a : ti##b;                                    \
    td##a = _fa; td##b = _fb; ti##a = _ia; ti##b = _ib;                    \
  }
#define TK_BUBBLE                                                          \
  TK_SW(18, 19) TK_SW(17, 18) TK_SW(16, 17) TK_SW(15, 16) TK_SW(14, 15)    \
  TK_SW(13, 14) TK_SW(12, 13) TK_SW(11, 12) TK_SW(10, 11) TK_SW(9, 10)     \
  TK_SW(8, 9) TK_SW(7, 8) TK_SW(6, 7) TK_SW(5, 6) TK_SW(4, 5)              \
  TK_SW(3, 4) TK_SW(2, 3) TK_SW(1, 2) TK_SW(0, 1)

__global__ __launch_bounds__(128, 4) void merge_kernel(
    const float* __restrict__ cd, const int* __restrict__ ci,
    int* __restrict__ idxf) {
  const int b = blockIdx.y;
  const int n = blockIdx.x * 128 + threadIdx.x;

  TK_LIST(TK_DECL)

  for (int ch = 0; ch < NCH; ++ch) {
    const size_t base = ((size_t)(b * NCH + ch) * KNN) * NN + n;
    for (int s = 0; s < KNN; ++s) {
      const float d = cd[base + (size_t)s * NN];
      const int j = ci[base + (size_t)s * NN];
      if ((d < td19) || ((d == td19) && (j < ti19))) {
        td19 = d;
        ti19 = j;
        TK_BUBBLE
      }
    }
  }

#define TK_STI(k) idxf[((size_t)b * KNN + (k)) * NN + n] = ti##k;
  TK_LIST(TK_STI)
#undef TK_STI
}

// ---------------------------------------------------------------------------
// Kernel 4: gather + max + leaky + transposed store (bf16 A).
// ---------------------------------------------------------------------------
__global__ __launch_bounds__(128) void gather_kernel(
    const unsigned short* __restrict__ Ab16, const float* __restrict__ Q,
    const int* __restrict__ idxf, float* __restrict__ out) {
  __shared__ int jidx[KNN][32];
  __shared__ float ob[32][OO + 1];

  const int b = blockIdx.y;
  const int n0 = blockIdx.x * 32;
  const int t = threadIdx.x;

  for (int e = t; e < KNN * 32; e += 128) {
    const int k = e >> 5, ii = e & 31;
    jidx[k][ii] = idxf[((size_t)b * KNN + k) * NN + n0 + ii];
  }
  __syncthreads();

  const unsigned short* Ab = Ab16 + (size_t)b * NN * OO;
  const float* Qb = Q + (size_t)b * NN * OO;

  for (int ii = 0; ii < 32; ++ii) {
    float m = -1e30f;
#pragma unroll
    for (int k = 0; k < KNN; ++k) {
      const unsigned v = Ab[(size_t)jidx[k][ii] * OO + t];
      m = fmaxf(m, __uint_as_float(v << 16));
    }
    const float h = m + Qb[(size_t)(n0 + ii) * OO + t];
    ob[ii][t] = (h >= 0.f) ? h : 0.2f * h;
  }
  __syncthreads();

  float* ou = out + (size_t)b * OO * NN;
  for (int e = t; e < 32 * OO; e += 128) {
    const int ii = e & 31, oo = e >> 5;
    ou[(size_t)oo * NN + n0 + ii] = ob[ii][oo];
  }
}

// ---------------------------------------------------------------------------
extern "C" void kernel_launch(void* const* d_in, const int* in_sizes, int n_in,
                              void* d_out, int out_size, void* d_ws,
                              size_t ws_size, hipStream_t stream) {
  (void)in_sizes;
  (void)n_in;
  (void)out_size;
  (void)ws_size;
  const float* x = (const float*)d_in[0];
  const float* W = (const float*)d_in[1];
  const float* bias = (const float*)d_in[2];
  float* out = (float*)d_out;

  char* ws = (char*)d_ws;
  size_t off = 0;
  unsigned short* Ab16 = (unsigned short*)(ws + off);
  off += (size_t)BB * NN * OO * 2;              // 8 MB
  float* Q = (float*)(ws + off);
  off += (size_t)BB * NN * OO * 4;              // 16 MB
  float* xsq = (float*)(ws + off);
  off += (size_t)BB * NN * 4;                   // 128 KB
  unsigned short* xsp = (unsigned short*)(ws + off);
  off += (size_t)BB * NN * SPLITW * 2;          // 12.6 MB
  float* cd = (float*)(ws + off);
  off += (size_t)BB * NCH * KNN * NN * 4;       // 10.5 MB
  int* ci = (int*)(ws + off);
  off += (size_t)BB * NCH * KNN * NN * 4;       // 10.5 MB
  int* idxf = (int*)(ws + off);
  off += (size_t)BB * KNN * NN * 4;             // 2.6 MB

  precompute_kernel<<<dim3(NN / 128, BB), 128, 0, stream>>>(x, W, bias, Ab16,
                                                            Q, xsq, xsp);
  knn_kernel<<<dim3(NN / 64, BB), 256, 0, stream>>>(xsp, xsq, cd, ci);
  merge_kernel<<<dim3(NN / 128, BB), 128, 0, stream>>>(cd, ci, idxf);
  gather_kernel<<<dim3(NN / 32, BB), 128, 0, stream>>>(Ab16, Q, idxf, out);
}